// Round 1
// baseline (916.173 us; speedup 1.0000x reference)
//
#include <hip/hip_runtime.h>
#include <math.h>

typedef __attribute__((ext_vector_type(8))) short short8;
typedef __attribute__((ext_vector_type(4))) float f32x4;

#define MFMA16 __builtin_amdgcn_mfma_f32_16x16x32_bf16

namespace {

constexpr float kI180 = 0.07453559924999299f;  // 1/sqrt(180)
constexpr float kI90  = 0.10540925533894598f;  // 1/sqrt(90)
constexpr float kTwoPi = 6.283185307179586f;

__device__ inline unsigned short f2b(float f) {
  unsigned u = __builtin_bit_cast(unsigned, f);
  u += 0x7fffu + ((u >> 16) & 1u);
  return (unsigned short)(u >> 16);
}
__device__ inline unsigned pack2(float a, float b) {
  return (unsigned)f2b(a) | ((unsigned)f2b(b) << 16);
}

// ---------------------------------------------------------------- prep ------
// Builds all bf16 constant matrices (B-operands, layout Bt[n][k], k contiguous)
// with zero padding embedded, plus fp32 biases.
__global__ void prep_k(short* cTw, short* cThf, short* cThi, short* cW1,
                       short* cW2, short* cTwi, float* fB1, float* fB2,
                       const float* __restrict__ w1, const float* __restrict__ b1,
                       const float* __restrict__ w2, const float* __restrict__ b2) {
  int gid = blockIdx.x * blockDim.x + threadIdx.x;
  int gs = gridDim.x * blockDim.x;
  // cTw[96][192]: n=(ri,w') (48+48), k=w. forward W-DFT.
  for (int i = gid; i < 96 * 192; i += gs) {
    int n = i / 192, k = i % 192;
    int ri = n / 48, wp = n % 48;
    float v = 0.f;
    if (wp < 46 && k < 180) {
      int r = (k * wp) % 180;
      float s, c;
      sincosf(kTwoPi * (float)r / 180.f, &s, &c);
      v = (ri == 0) ? c * kI180 : -s * kI180;
    }
    cTw[i] = (short)f2b(v);
  }
  // cThf[192][192]: n=(rj,h'), k=(ri,h). forward H-DFT.
  // cThi[192][192]: n=(rj,h),  k=(ri,h'). inverse H-DFT.
  for (int i = gid; i < 192 * 192; i += gs) {
    int n = i / 192, k = i % 192;
    int rj = n / 96, hp = n % 96;
    int ri = k / 96, h = k % 96;
    float vf = 0.f, vi = 0.f;
    if (hp < 90 && h < 90) {
      int r = (h * hp) % 90;
      float s, c;
      sincosf(kTwoPi * (float)r / 90.f, &s, &c);
      c *= kI90; s *= kI90;
      vf = (rj == 0) ? ((ri == 0) ? c : s) : ((ri == 0) ? -s : c);
      vi = (rj == 0) ? ((ri == 0) ? c : -s) : ((ri == 0) ? s : c);
    }
    cThf[i] = (short)f2b(vf);
    cThi[i] = (short)f2b(vi);
  }
  // cW1/cW2 [8][192][192]: per block n: Bt[j=(rj,o)][k=(ri,ci)]
  for (int i = gid; i < 8 * 192 * 192; i += gs) {
    int n = i / 36864, r2 = i % 36864;
    int j = r2 / 192, k = r2 % 192;
    int rj = j / 96, o = j % 96;
    int ri = k / 96, ci = k % 96;
    {
      float W0 = w1[((size_t)(n * 96 + ci)) * 96 + o];
      float W1v = w1[((size_t)((8 + n) * 96 + ci)) * 96 + o];
      float v = (rj == 0) ? ((ri == 0) ? W0 : -W1v) : ((ri == 0) ? W1v : W0);
      cW1[i] = (short)f2b(v);
    }
    {
      float W0 = w2[((size_t)(n * 96 + ci)) * 96 + o];
      float W1v = w2[((size_t)((8 + n) * 96 + ci)) * 96 + o];
      float v = (rj == 0) ? ((ri == 0) ? W0 : -W1v) : ((ri == 0) ? W1v : W0);
      cW2[i] = (short)f2b(v);
    }
  }
  // cTwi[192][96]: n=w, k=(ri,w'). inverse W (real output, Hermitian fold).
  for (int i = gid; i < 192 * 96; i += gs) {
    int n = i / 96, k = i % 96;
    int ri = k / 48, wp = k % 48;
    float v = 0.f;
    if (n < 180 && wp < 46) {
      int r = (n * wp) % 180;
      float s, c;
      sincosf(kTwoPi * (float)r / 180.f, &s, &c);
      if (ri == 0) v = ((wp == 0) ? 1.f : 2.f) * c * kI180;
      else v = (wp == 0) ? 0.f : -2.f * s * kI180;
    }
    cTwi[i] = (short)f2b(v);
  }
  // biases fp32: fB[n][j=(rj,o)]
  for (int i = gid; i < 8 * 192; i += gs) {
    int n = i / 192, j = i % 192;
    int rj = j / 96, o = j % 96;
    fB1[i] = b1[(size_t)(rj * 8 + n) * 96 + o];
    fB2[i] = b2[(size_t)(rj * 8 + n) * 96 + o];
  }
}

// ---------------------------------------------------------------- S1 --------
// Per (b,h): C[c 64][n=(ri,w') 96] = A(xT staged)[64][192w] * Bt(cTw)[96][192].
// LDS holds ONLY the transposed A tile (XOR-swizzled dword columns to kill the
// 8-way transpose-write bank conflict); B fragments come straight from cTw
// (36.9 KB, L1/L2-resident). LDS 64000->25600 B => 2->~5 blocks/CU.
__global__ __launch_bounds__(256, 4) void s1_k(const float* __restrict__ x,
                                               const short* __restrict__ cTw,
                                               short* __restrict__ X1a) {
  __shared__ short Al[64 * 200];
  int t = threadIdx.x;
  int bh = blockIdx.x;
  int c0 = blockIdx.y * 64;
  unsigned* Ad = (unsigned*)Al;
  const float* xb = x + (size_t)bh * 180 * 768 + c0;
  // swizzle: row c, logical dword col v -> physical v ^ (((c>>2)&7)<<2).
  // bits>=2 only => 16B blocks stay contiguous; write group (c stride 4,
  // same col) now spans 8 banks (2-way, free) instead of 2 (8-way).
  for (int q = t; q < 90 * 16; q += 256) {
    int cq = q % 16, wp = q / 16;
    int w0 = wp * 2;
    const float4 a0 = *(const float4*)(xb + (size_t)w0 * 768 + cq * 4);
    const float4 a1 = *(const float4*)(xb + (size_t)(w0 + 1) * 768 + cq * 4);
    int cb = cq * 4;
    int swA = (((cb + 0) >> 2) & 7) << 2;  // rows cb..cb+3 share c>>2 = cq
    Ad[(cb + 0) * 100 + (wp ^ swA)] = pack2(a0.x, a1.x);
    Ad[(cb + 1) * 100 + (wp ^ swA)] = pack2(a0.y, a1.y);
    Ad[(cb + 2) * 100 + (wp ^ swA)] = pack2(a0.z, a1.z);
    Ad[(cb + 3) * 100 + (wp ^ swA)] = pack2(a0.w, a1.w);
  }
  for (int q = t; q < 64 * 6; q += 256) {
    int c = q / 6, wp = 90 + q % 6;
    int sw = ((c >> 2) & 7) << 2;
    Ad[c * 100 + (wp ^ sw)] = 0u;
  }
  __syncthreads();
  int lane = t & 63, wv = t >> 6, ln = lane & 15, qd = lane >> 4;
  f32x4 z = {0.f, 0.f, 0.f, 0.f};
  f32x4 acc[6];
#pragma unroll
  for (int i = 0; i < 6; ++i) acc[i] = z;
  int arowc = wv * 16 + ln;
  int sw = ((arowc >> 2) & 7) << 2;
  const short* Bb = cTw + (size_t)ln * 192;
#pragma unroll
  for (int kc = 0; kc < 6; ++kc) {
    int kod = kc * 16 + qd * 4;  // logical dword col
    short8 av = *(const short8*)&Al[arowc * 200 + (kod ^ sw) * 2];
    int ko = kc * 32 + qd * 8;
#pragma unroll
    for (int nf = 0; nf < 6; ++nf) {
      short8 bv = *(const short8*)&Bb[(size_t)nf * 16 * 192 + ko];
      acc[nf] = MFMA16(av, bv, acc[nf], 0, 0, 0);
    }
  }
  short* dst = X1a + (size_t)bh * 96 * 768;
  int cbase = c0 + wv * 16 + qd * 4;
#pragma unroll
  for (int nf = 0; nf < 6; ++nf) {
    int n = nf * 16 + ln;
    short4 v;
    v.x = (short)f2b(acc[nf][0]);
    v.y = (short)f2b(acc[nf][1]);
    v.z = (short)f2b(acc[nf][2]);
    v.w = (short)f2b(acc[nf][3]);
    *(short4*)&dst[(size_t)n * 768 + cbase] = v;
  }
}

// ---------------------------------------------------------------- T1 --------
// X1a[b][h][ri*48+w'][c] -> X1b[b][(w'*768+c)][(ri*96+h) 192], zero h-pads.
__global__ __launch_bounds__(256) void t1_k(const short* __restrict__ X1a,
                                            short* __restrict__ X1b) {
  __shared__ short L[64 * 104];
  unsigned* Ld = (unsigned*)L;
  int t = threadIdx.x;
  int gx = blockIdx.x;
  int c0 = blockIdx.y * 64;
  int b = gx / 92, r = gx % 92;
  int ri = r / 46, wp = r % 46;
  const short* src = X1a + ((size_t)(b * 90) * 96 + ri * 48 + wp) * 768 + c0;
  for (int q = t; q < 45 * 8; q += 256) {
    int hp = q % 45, seg = q / 45;
    int h0 = hp * 2;
    short8 r0 = *(const short8*)&src[(size_t)h0 * 73728 + seg * 8];
    short8 r1 = *(const short8*)&src[(size_t)(h0 + 1) * 73728 + seg * 8];
#pragma unroll
    for (int i = 0; i < 8; ++i) {
      int c = seg * 8 + i;
      Ld[c * 52 + hp] = (unsigned)(unsigned short)r0[i] |
                        ((unsigned)(unsigned short)r1[i] << 16);
    }
  }
  for (int q = t; q < 64 * 3; q += 256) {
    int c = q / 3, hp = 45 + q % 3;
    Ld[c * 52 + hp] = 0u;
  }
  __syncthreads();
  short* dst = X1b + (size_t)b * 35328 * 192 + ((size_t)wp * 768 + c0) * 192 + ri * 96;
  for (int q = t; q < 64 * 12; q += 256) {
    int c = q / 12, seg = q % 12;
    short8 v = *(const short8*)&L[c * 104 + seg * 8];
    *(short8*)&dst[(size_t)c * 192 + seg * 8] = v;
  }
}

// ---------------------------------------------------------------- S2/S4 -----
// Per b: C[m=(w'c) 35328][n 192] = A(data)[m][192] * Bt[n][192]; transposed
// store -> dst[b][n][m]. A rows are k-contiguous in global memory, exactly the
// MFMA fragment layout => NO LDS, NO barriers: both A and B fragments are
// loaded per-lane from global (A once per kc, reused across nf; B L2-resident).
__global__ __launch_bounds__(256, 4) void s24_k(const short* __restrict__ Asrc,
                                                const short* __restrict__ Bsrc,
                                                short* __restrict__ dst) {
  int t = threadIdx.x;
  int mt = blockIdx.x, nh = blockIdx.y, b = blockIdx.z;
  int lane = t & 63, wv = t >> 6, ln = lane & 15, qd = lane >> 4;
  const short* Ab = Asrc + ((size_t)b * 35328 + (size_t)mt * 64 + wv * 16 + ln) * 192;
  const short* Bb = Bsrc + (size_t)(nh * 96 + ln) * 192;
  f32x4 z = {0.f, 0.f, 0.f, 0.f};
  f32x4 acc[6];
#pragma unroll
  for (int i = 0; i < 6; ++i) acc[i] = z;
#pragma unroll
  for (int kc = 0; kc < 6; ++kc) {
    int ko = kc * 32 + qd * 8;
    short8 av = *(const short8*)&Ab[ko];
#pragma unroll
    for (int nf = 0; nf < 6; ++nf) {
      short8 bv = *(const short8*)&Bb[(size_t)nf * 16 * 192 + ko];
      acc[nf] = MFMA16(av, bv, acc[nf], 0, 0, 0);
    }
  }
  size_t m0 = (size_t)mt * 64 + wv * 16 + qd * 4;
  short* db = dst + (size_t)b * 192 * 35328;
#pragma unroll
  for (int nf = 0; nf < 6; ++nf) {
    int n = nh * 96 + nf * 16 + ln;
    short4 v;
    v.x = (short)f2b(acc[nf][0]);
    v.y = (short)f2b(acc[nf][1]);
    v.z = (short)f2b(acc[nf][2]);
    v.w = (short)f2b(acc[nf][3]);
    *(short4*)&db[(size_t)n * 35328 + m0] = v;
  }
}

// ---------------------------------------------------------------- S3a -------
// MLP layer 1: A gathered per-lane from X2 (16B granules, 96-short aligned),
// B=cW1[n] direct from global, relu(.+b). Only LDS use: 13.3 KB output
// retile buffer. One barrier total.
__global__ __launch_bounds__(256, 4) void s3a_k(const short* __restrict__ X2,
                                                const short* __restrict__ cW1,
                                                const float* __restrict__ fB1,
                                                short* __restrict__ O1) {
  __shared__ short R[64 * 104];
  int t = threadIdx.x;
  int mt = blockIdx.x;
  int n = blockIdx.y >> 1, nh = blockIdx.y & 1;
  int lane = t & 63, wv = t >> 6, ln = lane & 15, qd = lane >> 4;
  int m = wv * 16 + ln;
  int p = mt * 64 + m;
  if (p > 16559) p = 16559;
  int pb = p / 4140, rem = p % 4140;
  int hp = rem / 46, wp = rem % 46;
  const short* Ap = X2 + ((size_t)pb * 192 + hp) * 35328 + (size_t)wp * 768 + n * 96;
  const short* Bb = cW1 + (size_t)n * 36864 + (size_t)(nh * 96 + ln) * 192;
  f32x4 z = {0.f, 0.f, 0.f, 0.f};
  f32x4 acc[6];
#pragma unroll
  for (int i = 0; i < 6; ++i) acc[i] = z;
#pragma unroll
  for (int kc = 0; kc < 6; ++kc) {
    int ko = kc * 32 + qd * 8;
    int ri = kc / 3;  // compile-time under unroll; ko<96 iff kc<3
    int kl = ko - ri * 96;
    short8 av = *(const short8*)&Ap[(size_t)ri * 96 * 35328 + kl];
#pragma unroll
    for (int nf = 0; nf < 6; ++nf) {
      short8 bv = *(const short8*)&Bb[(size_t)nf * 16 * 192 + ko];
      acc[nf] = MFMA16(av, bv, acc[nf], 0, 0, 0);
    }
  }
#pragma unroll
  for (int nf = 0; nf < 6; ++nf) {
    float bias = fB1[n * 192 + nh * 96 + nf * 16 + ln];
#pragma unroll
    for (int r = 0; r < 4; ++r) {
      float v = acc[nf][r] + bias;
      v = v > 0.f ? v : 0.f;
      R[(wv * 16 + qd * 4 + r) * 104 + nf * 16 + ln] = (short)f2b(v);
    }
  }
  __syncthreads();
  for (int q = t; q < 64 * 12; q += 256) {
    int pr = q / 12, seg = q % 12;
    int pp = mt * 64 + pr;
    if (pp < 16560) {
      *(short8*)&O1[((size_t)n * 16576 + pp) * 192 + nh * 96 + seg * 8] =
          *(const short8*)&R[pr * 104 + seg * 8];
    }
  }
}

// ---------------------------------------------------------------- S3b -------
// MLP layer 2: A = O1 rows (k-contiguous in global => direct fragment loads),
// B=cW2[n] direct, softshrink(.+b). NO LDS, NO barriers.
__global__ __launch_bounds__(256, 4) void s3b_k(const short* __restrict__ O1,
                                                const short* __restrict__ cW2,
                                                const float* __restrict__ fB2,
                                                short* __restrict__ O2) {
  int t = threadIdx.x;
  int mt = blockIdx.x;
  int n = blockIdx.y >> 1, nh = blockIdx.y & 1;
  int lane = t & 63, wv = t >> 6, ln = lane & 15, qd = lane >> 4;
  int p = mt * 64 + wv * 16 + ln;
  if (p > 16559) p = 16559;
  const short* Ab = O1 + ((size_t)n * 16576 + p) * 192;
  const short* Bb = cW2 + (size_t)n * 36864 + (size_t)(nh * 96 + ln) * 192;
  f32x4 z = {0.f, 0.f, 0.f, 0.f};
  f32x4 acc[6];
#pragma unroll
  for (int i = 0; i < 6; ++i) acc[i] = z;
#pragma unroll
  for (int kc = 0; kc < 6; ++kc) {
    int ko = kc * 32 + qd * 8;
    short8 av = *(const short8*)&Ab[ko];
#pragma unroll
    for (int nf = 0; nf < 6; ++nf) {
      short8 bv = *(const short8*)&Bb[(size_t)nf * 16 * 192 + ko];
      acc[nf] = MFMA16(av, bv, acc[nf], 0, 0, 0);
    }
  }
  size_t p0 = (size_t)mt * 64 + wv * 16 + qd * 4;
  if (p0 < 16560) {
#pragma unroll
    for (int nf = 0; nf < 6; ++nf) {
      int j = nh * 96 + nf * 16 + ln;
      float bias = fB2[n * 192 + j];
      short4 v;
      float s0;
      s0 = acc[nf][0] + bias; s0 = fabsf(s0) > 0.01f ? copysignf(fabsf(s0) - 0.01f, s0) : 0.f; v.x = (short)f2b(s0);
      s0 = acc[nf][1] + bias; s0 = fabsf(s0) > 0.01f ? copysignf(fabsf(s0) - 0.01f, s0) : 0.f; v.y = (short)f2b(s0);
      s0 = acc[nf][2] + bias; s0 = fabsf(s0) > 0.01f ? copysignf(fabsf(s0) - 0.01f, s0) : 0.f; v.z = (short)f2b(s0);
      s0 = acc[nf][3] + bias; s0 = fabsf(s0) > 0.01f ? copysignf(fabsf(s0) - 0.01f, s0) : 0.f; v.w = (short)f2b(s0);
      *(short4*)&O2[((size_t)n * 192 + j) * 16576 + p0] = v;
    }
  }
}

// ---------------------------------------------------------------- T2 --------
// O2[n][(rj,o)][pos] -> X3[b][(w'*768+n*96+o)][(rj*96+h')], zero h'-pads.
__global__ __launch_bounds__(256) void t2_k(const short* __restrict__ O2,
                                            short* __restrict__ X3) {
  __shared__ short L[16 * 1488];
  int t = threadIdx.x;
  int gx = blockIdx.x;
  int ht = gx % 3; gx /= 3;
  int ot = gx % 6; gx /= 6;
  int rj = gx % 2; gx /= 2;
  int n = gx % 8;
  int b = gx / 8;
  int h0 = ht * 32;
  int nh = min(32, 90 - h0);
  int o0 = ot * 16;
  int posbase = (b * 90 + h0) * 46;
  int pa = posbase & ~7;
  int d = posbase - pa;
  int vlen = d + 46 * nh;
  int segs = (vlen + 7) / 8;
  for (int q = t; q < 16 * 186; q += 256) {
    int orl = q / 186, seg = q % 186;
    if (seg < segs) {
      short8 v = *(const short8*)&O2[((size_t)n * 192 + rj * 96 + o0 + orl) * 16576 +
                                     pa + seg * 8];
      int base = seg * 8;
      if (base >= d && base + 8 <= vlen) {
        *(short8*)&L[orl * 1488 + base] = v;
      } else {
#pragma unroll
        for (int i = 0; i < 8; ++i) {
          int col = base + i;
          L[orl * 1488 + col] = (col >= d && col < vlen) ? v[i] : (short)0;
        }
      }
    } else {
      short8 zz = {0, 0, 0, 0, 0, 0, 0, 0};
      *(short8*)&L[orl * 1488 + seg * 8] = zz;
    }
  }
  __syncthreads();
  short* dst = X3 + (size_t)b * 35328 * 192;
  for (int q = t; q < 46 * 64; q += 256) {
    int wp = q >> 6;
    int rem = q & 63;
    int orl = rem >> 2, seg = rem & 3;
    short8 v;
#pragma unroll
    for (int i = 0; i < 8; ++i) {
      int hrel = seg * 8 + i;
      v[i] = L[orl * 1488 + d + hrel * 46 + wp];
    }
    *(short8*)&dst[((size_t)wp * 768 + n * 96 + o0 + orl) * 192 + rj * 96 + h0 +
                   seg * 8] = v;
  }
}

// ---------------------------------------------------------------- S5 --------
// Per (b,h): C[c 64][w 192] = A(X4 gathered)[64][96] * Bt(cTwi)[192][96];
// B fragments direct from cTwi (36.9 KB, L1/L2-resident); LDS holds only the
// 13.3 KB transposed A tile. Epilogue: + x residual, fp32 store.
__global__ __launch_bounds__(256, 4) void s5_k(const short* __restrict__ X4,
                                               const short* __restrict__ cTwi,
                                               const float* __restrict__ x,
                                               float* __restrict__ out) {
  __shared__ short Al[64 * 104];
  int t = threadIdx.x;
  int bh = blockIdx.x;
  int c0 = blockIdx.y * 64;
  int b = bh / 90, h = bh % 90;
  for (int q = t; q < 96 * 8; q += 256) {
    int k = q % 96, cs = q / 96;
    int ri = k / 48, wp = k % 48;
    if (wp > 45) wp = 45;
    short8 v = *(const short8*)&X4[((size_t)b * 192 + ri * 96 + h) * 35328 +
                                   (size_t)wp * 768 + c0 + cs * 8];
#pragma unroll
    for (int i = 0; i < 8; ++i) Al[(cs * 8 + i) * 104 + k] = v[i];
  }
  __syncthreads();
  int lane = t & 63, wv = t >> 6, ln = lane & 15, qd = lane >> 4;
  f32x4 z = {0.f, 0.f, 0.f, 0.f};
  f32x4 acc[12];
#pragma unroll
  for (int i = 0; i < 12; ++i) acc[i] = z;
  int arow = (wv * 16 + ln) * 104;
  const short* Bb = cTwi + (size_t)ln * 96;
#pragma unroll
  for (int kc = 0; kc < 3; ++kc) {
    int ko = kc * 32 + qd * 8;
    short8 av = *(const short8*)&Al[arow + ko];
#pragma unroll
    for (int nf = 0; nf < 12; ++nf) {
      short8 bv = *(const short8*)&Bb[(size_t)nf * 16 * 96 + ko];
      acc[nf] = MFMA16(av, bv, acc[nf], 0, 0, 0);
    }
  }
  int cb = c0 + wv * 16 + qd * 4;
  const float* xr = x + (size_t)bh * 180 * 768;
  float* ob = out + (size_t)bh * 180 * 768;
#pragma unroll
  for (int nf = 0; nf < 12; ++nf) {
    int w = nf * 16 + ln;
    if (w < 180) {
      float4 xv = *(const float4*)&xr[(size_t)w * 768 + cb];
      float4 o;
      o.x = acc[nf][0] + xv.x;
      o.y = acc[nf][1] + xv.y;
      o.z = acc[nf][2] + xv.z;
      o.w = acc[nf][3] + xv.w;
      *(float4*)&ob[(size_t)w * 768 + cb] = o;
    }
  }
}

}  // namespace

extern "C" void kernel_launch(void* const* d_in, const int* in_sizes, int n_in,
                              void* d_out, int out_size, void* d_ws, size_t ws_size,
                              hipStream_t stream) {
  const float* x = (const float*)d_in[0];
  const float* w1 = (const float*)d_in[1];
  const float* b1 = (const float*)d_in[2];
  const float* w2 = (const float*)d_in[3];
  const float* b2 = (const float*)d_in[4];
  float* out = (float*)d_out;

  size_t off = 0;
  auto carve = [&](size_t bytes) -> char* {
    char* p = (char*)d_ws + off;
    off += (bytes + 255) & ~(size_t)255;
    return p;
  };
  short* cTw = (short*)carve(96 * 192 * 2);
  short* cThf = (short*)carve(192 * 192 * 2);
  short* cThi = (short*)carve(192 * 192 * 2);
  short* cW1 = (short*)carve(8 * 192 * 192 * 2);
  short* cW2 = (short*)carve(8 * 192 * 192 * 2);
  short* cTwi = (short*)carve(192 * 96 * 2);
  float* fB1 = (float*)carve(8 * 192 * 4);
  float* fB2 = (float*)carve(8 * 192 * 4);
  const size_t SLOT = 27131904;  // shorts (= 4*192*35328)
  short* slotA = (short*)carve(SLOT * 2);
  short* slotB = (short*)carve(SLOT * 2);
  // liveness-based aliasing:
  short* X1a = slotA;  // S1 -> T1
  short* X1b = slotB;  // T1 -> S2
  short* X2 = slotA;   // S2 -> S3a
  short* O1 = slotB;   // S3a -> S3b
  short* O2 = slotA;   // S3b -> T2
  short* X3 = slotB;   // T2 -> S4
  short* X4 = slotA;   // S4 -> S5

  prep_k<<<512, 256, 0, stream>>>(cTw, cThf, cThi, cW1, cW2, cTwi, fB1, fB2,
                                  w1, b1, w2, b2);
  s1_k<<<dim3(360, 12), 256, 0, stream>>>(x, cTw, X1a);
  t1_k<<<dim3(368, 12), 256, 0, stream>>>(X1a, X1b);
  s24_k<<<dim3(552, 2, 4), 256, 0, stream>>>(X1b, cThf, X2);
  s3a_k<<<dim3(259, 16), 256, 0, stream>>>(X2, cW1, fB1, O1);
  s3b_k<<<dim3(259, 16), 256, 0, stream>>>(O1, cW2, fB2, O2);
  t2_k<<<dim3(1152), 256, 0, stream>>>(O2, X3);
  s24_k<<<dim3(552, 2, 4), 256, 0, stream>>>(X3, cThi, X4);
  s5_k<<<dim3(360, 12), 256, 0, stream>>>(X4, cTwi, x, out);
}

// Round 2
// 613.885 us; speedup vs baseline: 1.4924x; 1.4924x over previous
//
#include <hip/hip_runtime.h>
#include <math.h>

typedef __attribute__((ext_vector_type(8))) short short8;
typedef __attribute__((ext_vector_type(4))) float f32x4;

#define MFMA16 __builtin_amdgcn_mfma_f32_16x16x32_bf16

namespace {

constexpr float kI180 = 0.07453559924999299f;  // 1/sqrt(180)
constexpr float kI90  = 0.10540925533894598f;  // 1/sqrt(90)
constexpr float kTwoPi = 6.283185307179586f;

__device__ inline unsigned short f2b(float f) {
  unsigned u = __builtin_bit_cast(unsigned, f);
  u += 0x7fffu + ((u >> 16) & 1u);
  return (unsigned short)(u >> 16);
}

// ---------------------------------------------------------------- prep ------
__global__ void prep_k(short* cTw, short* cThf, short* cThi, short* cW1,
                       short* cW2, short* cTwi, float* fB1, float* fB2,
                       const float* __restrict__ w1, const float* __restrict__ b1,
                       const float* __restrict__ w2, const float* __restrict__ b2) {
  int gid = blockIdx.x * blockDim.x + threadIdx.x;
  int gs = gridDim.x * blockDim.x;
  // cTw[96][192]: n=(ri,w') (48+48), k=w. forward W-DFT.
  for (int i = gid; i < 96 * 192; i += gs) {
    int n = i / 192, k = i % 192;
    int ri = n / 48, wp = n % 48;
    float v = 0.f;
    if (wp < 46 && k < 180) {
      int r = (k * wp) % 180;
      float s, c;
      sincosf(kTwoPi * (float)r / 180.f, &s, &c);
      v = (ri == 0) ? c * kI180 : -s * kI180;
    }
    cTw[i] = (short)f2b(v);
  }
  // cThf[192][192]: n=(rj,h'), k=(ri,h). forward H-DFT.
  // cThi[192][192]: n=(rj,h),  k=(ri,h'). inverse H-DFT.
  for (int i = gid; i < 192 * 192; i += gs) {
    int n = i / 192, k = i % 192;
    int rj = n / 96, hp = n % 96;
    int ri = k / 96, h = k % 96;
    float vf = 0.f, vi = 0.f;
    if (hp < 90 && h < 90) {
      int r = (h * hp) % 90;
      float s, c;
      sincosf(kTwoPi * (float)r / 90.f, &s, &c);
      c *= kI90; s *= kI90;
      vf = (rj == 0) ? ((ri == 0) ? c : s) : ((ri == 0) ? -s : c);
      vi = (rj == 0) ? ((ri == 0) ? c : -s) : ((ri == 0) ? s : c);
    }
    cThf[i] = (short)f2b(vf);
    cThi[i] = (short)f2b(vi);
  }
  // cW1/cW2 [8][192][192]: per block n: Bt[j=(rj,o)][k=(ri,ci)]
  for (int i = gid; i < 8 * 192 * 192; i += gs) {
    int n = i / 36864, r2 = i % 36864;
    int j = r2 / 192, k = r2 % 192;
    int rj = j / 96, o = j % 96;
    int ri = k / 96, ci = k % 96;
    {
      float W0 = w1[((size_t)(n * 96 + ci)) * 96 + o];
      float W1v = w1[((size_t)((8 + n) * 96 + ci)) * 96 + o];
      float v = (rj == 0) ? ((ri == 0) ? W0 : -W1v) : ((ri == 0) ? W1v : W0);
      cW1[i] = (short)f2b(v);
    }
    {
      float W0 = w2[((size_t)(n * 96 + ci)) * 96 + o];
      float W1v = w2[((size_t)((8 + n) * 96 + ci)) * 96 + o];
      float v = (rj == 0) ? ((ri == 0) ? W0 : -W1v) : ((ri == 0) ? W1v : W0);
      cW2[i] = (short)f2b(v);
    }
  }
  // cTwi[192][96]: n=w, k=(ri,w'). inverse W (real output, Hermitian fold).
  for (int i = gid; i < 192 * 96; i += gs) {
    int n = i / 96, k = i % 96;
    int ri = k / 48, wp = k % 48;
    float v = 0.f;
    if (n < 180 && wp < 46) {
      int r = (n * wp) % 180;
      float s, c;
      sincosf(kTwoPi * (float)r / 180.f, &s, &c);
      if (ri == 0) v = ((wp == 0) ? 1.f : 2.f) * c * kI180;
      else v = (wp == 0) ? 0.f : -2.f * s * kI180;
    }
    cTwi[i] = (short)f2b(v);
  }
  // biases fp32: fB[n][j=(rj,o)]
  for (int i = gid; i < 8 * 192; i += gs) {
    int n = i / 192, j = i % 192;
    int rj = j / 96, o = j % 96;
    fB1[i] = b1[(size_t)(rj * 8 + n) * 96 + o];
    fB2[i] = b2[(size_t)(rj * 8 + n) * 96 + o];
  }
}

// ---------------------------------------------------------------- S1 --------
// Per (b,h): C[c 64][n=(ri,w') 96] = A(x direct-gather)[64][192w] * Bt(cTw LDS).
// No A-LDS: each lane batch-loads its 48 x dwords (16 lanes = one 64B line),
// converts in-register. B staged once, exact-unrolled two-phase copy.
// LDS 38.4 KB -> 4 blocks/CU.
__global__ __launch_bounds__(256, 4) void s1_k(const float* __restrict__ x,
                                               const short* __restrict__ cTw,
                                               short* __restrict__ X1a) {
  __shared__ short Bl[96 * 200];
  int t = threadIdx.x;
  int bh = blockIdx.x;
  int c0 = blockIdx.y * 64;
  // stage B (96x192 -> padded 200), batched: 2304 short8 / 256 = 9 exact.
  {
    short8 tb[9];
#pragma unroll
    for (int i = 0; i < 9; ++i) {
      int q = t + i * 256;
      int r = q / 24, s = q % 24;
      tb[i] = *(const short8*)&cTw[r * 192 + s * 8];
    }
#pragma unroll
    for (int i = 0; i < 9; ++i) {
      int q = t + i * 256;
      int r = q / 24, s = q % 24;
      *(short8*)&Bl[r * 200 + s * 8] = tb[i];
    }
  }
  int lane = t & 63, wv = t >> 6, ln = lane & 15, qd = lane >> 4;
  int c = c0 + wv * 16 + ln;
  const float* xc = x + (size_t)bh * 180 * 768 + c;
  // gather all 48 w-samples for this lane's channel (batched, clamped addr).
  float xv[48];
#pragma unroll
  for (int kc = 0; kc < 6; ++kc) {
#pragma unroll
    for (int j = 0; j < 8; ++j) {
      int w = kc * 32 + qd * 8 + j;
      int wl = w < 180 ? w : 0;
      xv[kc * 8 + j] = xc[(size_t)wl * 768];
    }
  }
  short8 a[6];
#pragma unroll
  for (int kc = 0; kc < 6; ++kc) {
#pragma unroll
    for (int j = 0; j < 8; ++j) {
      int w = kc * 32 + qd * 8 + j;
      float v = (w < 180) ? xv[kc * 8 + j] : 0.f;
      a[kc][j] = (short)f2b(v);
    }
  }
  __syncthreads();
  f32x4 z = {0.f, 0.f, 0.f, 0.f};
  f32x4 acc[6];
#pragma unroll
  for (int i = 0; i < 6; ++i) acc[i] = z;
#pragma unroll
  for (int kc = 0; kc < 6; ++kc) {
    int ko = kc * 32 + qd * 8;
#pragma unroll
    for (int nf = 0; nf < 6; ++nf) {
      short8 bv = *(const short8*)&Bl[(nf * 16 + ln) * 200 + ko];
      acc[nf] = MFMA16(a[kc], bv, acc[nf], 0, 0, 0);
    }
  }
  short* dst = X1a + (size_t)bh * 96 * 768;
  int cbase = c0 + wv * 16 + qd * 4;
#pragma unroll
  for (int nf = 0; nf < 6; ++nf) {
    int n = nf * 16 + ln;
    short4 v;
    v.x = (short)f2b(acc[nf][0]);
    v.y = (short)f2b(acc[nf][1]);
    v.z = (short)f2b(acc[nf][2]);
    v.w = (short)f2b(acc[nf][3]);
    *(short4*)&dst[(size_t)n * 768 + cbase] = v;
  }
}

// ---------------------------------------------------------------- T1 --------
// X1a[b][h][ri*48+w'][c] -> X1b[b][(w'*768+c)][(ri*96+h) 192], zero h-pads.
// Read loop seg-fastest (128B contiguous runs), unrolled 2.
__global__ __launch_bounds__(256) void t1_k(const short* __restrict__ X1a,
                                            short* __restrict__ X1b) {
  __shared__ short L[64 * 104];
  unsigned* Ld = (unsigned*)L;
  int t = threadIdx.x;
  int gx = blockIdx.x;
  int c0 = blockIdx.y * 64;
  int b = gx / 92, r = gx % 92;
  int ri = r / 46, wp = r % 46;
  const short* src = X1a + ((size_t)(b * 90) * 96 + ri * 48 + wp) * 768 + c0;
  short8 r0a[2], r1a[2];
#pragma unroll
  for (int i = 0; i < 2; ++i) {
    int q = t + i * 256;
    int ql = q < 360 ? q : 0;
    int seg = ql & 7, hp = ql >> 3;
    int h0 = hp * 2;
    r0a[i] = *(const short8*)&src[(size_t)h0 * 73728 + seg * 8];
    r1a[i] = *(const short8*)&src[(size_t)(h0 + 1) * 73728 + seg * 8];
  }
#pragma unroll
  for (int i = 0; i < 2; ++i) {
    int q = t + i * 256;
    if (q < 360) {
      int seg = q & 7, hp = q >> 3;
#pragma unroll
      for (int j = 0; j < 8; ++j) {
        int cch = seg * 8 + j;
        Ld[cch * 52 + hp] = (unsigned)(unsigned short)r0a[i][j] |
                            ((unsigned)(unsigned short)r1a[i][j] << 16);
      }
    }
  }
  for (int q = t; q < 64 * 3; q += 256) {
    int cch = q / 3, hp = 45 + q % 3;
    Ld[cch * 52 + hp] = 0u;
  }
  __syncthreads();
  short* dst = X1b + (size_t)b * 35328 * 192 + ((size_t)wp * 768 + c0) * 192 + ri * 96;
  for (int q = t; q < 64 * 12; q += 256) {
    int cch = q / 12, seg = q % 12;
    short8 v = *(const short8*)&L[cch * 104 + seg * 8];
    *(short8*)&dst[(size_t)cch * 192 + seg * 8] = v;
  }
}

// ---------------------------------------------------------------- S2/S4 -----
// Per b: C[m=(w'c) 35328][n 192] = A(data)[m][192] * Bt[n][192]; transposed
// store -> dst[b][n][m]. B staged in LDS (batched copy); A rows k-contiguous
// in global => 6 batched 16B fragment loads per lane, no A-LDS.
// LDS 38.4 KB -> 4 blocks/CU.
__global__ __launch_bounds__(256, 4) void s24_k(const short* __restrict__ Asrc,
                                                const short* __restrict__ Bsrc,
                                                short* __restrict__ dst) {
  __shared__ short Bl[96 * 200];
  int t = threadIdx.x;
  int mt = blockIdx.x, nh = blockIdx.y, b = blockIdx.z;
  {
    short8 tb[9];
#pragma unroll
    for (int i = 0; i < 9; ++i) {
      int q = t + i * 256;
      int r = q / 24, s = q % 24;
      tb[i] = *(const short8*)&Bsrc[(size_t)(nh * 96 + r) * 192 + s * 8];
    }
#pragma unroll
    for (int i = 0; i < 9; ++i) {
      int q = t + i * 256;
      int r = q / 24, s = q % 24;
      *(short8*)&Bl[r * 200 + s * 8] = tb[i];
    }
  }
  int lane = t & 63, wv = t >> 6, ln = lane & 15, qd = lane >> 4;
  const short* Ab = Asrc + ((size_t)b * 35328 + (size_t)mt * 64 + wv * 16 + ln) * 192;
  short8 a[6];
#pragma unroll
  for (int kc = 0; kc < 6; ++kc) a[kc] = *(const short8*)&Ab[kc * 32 + qd * 8];
  __syncthreads();
  f32x4 z = {0.f, 0.f, 0.f, 0.f};
  f32x4 acc[6];
#pragma unroll
  for (int i = 0; i < 6; ++i) acc[i] = z;
#pragma unroll
  for (int kc = 0; kc < 6; ++kc) {
    int ko = kc * 32 + qd * 8;
#pragma unroll
    for (int nf = 0; nf < 6; ++nf) {
      short8 bv = *(const short8*)&Bl[(nf * 16 + ln) * 200 + ko];
      acc[nf] = MFMA16(a[kc], bv, acc[nf], 0, 0, 0);
    }
  }
  size_t m0 = (size_t)mt * 64 + wv * 16 + qd * 4;
  short* db = dst + (size_t)b * 192 * 35328;
#pragma unroll
  for (int nf = 0; nf < 6; ++nf) {
    int n = nh * 96 + nf * 16 + ln;
    short4 v;
    v.x = (short)f2b(acc[nf][0]);
    v.y = (short)f2b(acc[nf][1]);
    v.z = (short)f2b(acc[nf][2]);
    v.w = (short)f2b(acc[nf][3]);
    *(short4*)&db[(size_t)n * 35328 + m0] = v;
  }
}

// ---------------------------------------------------------------- S3a -------
// MLP layer 1: A gathered per-lane from X2 (16B granules), B=cW1[n] staged in
// LDS; relu(.+b). Output retile buffer ALIASES the B tile (dead after MFMA).
// LDS 38.4 KB -> 4 blocks/CU.
__global__ __launch_bounds__(256, 4) void s3a_k(const short* __restrict__ X2,
                                                const short* __restrict__ cW1,
                                                const float* __restrict__ fB1,
                                                short* __restrict__ O1) {
  __shared__ short Sh[96 * 200];  // B tile, then reused as [64][104] retile
  int t = threadIdx.x;
  int mt = blockIdx.x;
  int n = blockIdx.y >> 1, nh = blockIdx.y & 1;
  {
    const short* Bsrc = cW1 + (size_t)n * 36864;
    short8 tb[9];
#pragma unroll
    for (int i = 0; i < 9; ++i) {
      int q = t + i * 256;
      int r = q / 24, s = q % 24;
      tb[i] = *(const short8*)&Bsrc[(size_t)(nh * 96 + r) * 192 + s * 8];
    }
#pragma unroll
    for (int i = 0; i < 9; ++i) {
      int q = t + i * 256;
      int r = q / 24, s = q % 24;
      *(short8*)&Sh[r * 200 + s * 8] = tb[i];
    }
  }
  int lane = t & 63, wv = t >> 6, ln = lane & 15, qd = lane >> 4;
  int p = mt * 64 + wv * 16 + ln;
  if (p > 16559) p = 16559;
  int pb = p / 4140, rem = p % 4140;
  int hp = rem / 46, wp = rem % 46;
  const short* Ap = X2 + ((size_t)pb * 192 + hp) * 35328 + (size_t)wp * 768 + n * 96;
  short8 a[6];
#pragma unroll
  for (int kc = 0; kc < 6; ++kc) {
    int ko = kc * 32 + qd * 8;
    int ri = kc / 3;  // compile-time under unroll
    int kl = ko - ri * 96;
    a[kc] = *(const short8*)&Ap[(size_t)ri * 96 * 35328 + kl];
  }
  __syncthreads();
  f32x4 z = {0.f, 0.f, 0.f, 0.f};
  f32x4 acc[6];
#pragma unroll
  for (int i = 0; i < 6; ++i) acc[i] = z;
#pragma unroll
  for (int kc = 0; kc < 6; ++kc) {
    int ko = kc * 32 + qd * 8;
#pragma unroll
    for (int nf = 0; nf < 6; ++nf) {
      short8 bv = *(const short8*)&Sh[(nf * 16 + ln) * 200 + ko];
      acc[nf] = MFMA16(a[kc], bv, acc[nf], 0, 0, 0);
    }
  }
  __syncthreads();  // all waves done reading B tile; reuse Sh as retile
#pragma unroll
  for (int nf = 0; nf < 6; ++nf) {
    float bias = fB1[n * 192 + nh * 96 + nf * 16 + ln];
#pragma unroll
    for (int r = 0; r < 4; ++r) {
      float v = acc[nf][r] + bias;
      v = v > 0.f ? v : 0.f;
      Sh[(wv * 16 + qd * 4 + r) * 104 + nf * 16 + ln] = (short)f2b(v);
    }
  }
  __syncthreads();
  for (int q = t; q < 64 * 12; q += 256) {
    int pr = q / 12, seg = q % 12;
    int pp = mt * 64 + pr;
    if (pp < 16560) {
      *(short8*)&O1[((size_t)n * 16576 + pp) * 192 + nh * 96 + seg * 8] =
          *(const short8*)&Sh[pr * 104 + seg * 8];
    }
  }
}

// ---------------------------------------------------------------- S3b -------
// MLP layer 2: A = O1 rows (k-contiguous => batched direct fragment loads),
// B=cW2[n] staged in LDS, softshrink(.+b). Transposed store.
// LDS 38.4 KB -> 4 blocks/CU.
__global__ __launch_bounds__(256, 4) void s3b_k(const short* __restrict__ O1,
                                                const short* __restrict__ cW2,
                                                const float* __restrict__ fB2,
                                                short* __restrict__ O2) {
  __shared__ short Bl[96 * 200];
  int t = threadIdx.x;
  int mt = blockIdx.x;
  int n = blockIdx.y >> 1, nh = blockIdx.y & 1;
  {
    const short* Bsrc = cW2 + (size_t)n * 36864;
    short8 tb[9];
#pragma unroll
    for (int i = 0; i < 9; ++i) {
      int q = t + i * 256;
      int r = q / 24, s = q % 24;
      tb[i] = *(const short8*)&Bsrc[(size_t)(nh * 96 + r) * 192 + s * 8];
    }
#pragma unroll
    for (int i = 0; i < 9; ++i) {
      int q = t + i * 256;
      int r = q / 24, s = q % 24;
      *(short8*)&Bl[r * 200 + s * 8] = tb[i];
    }
  }
  int lane = t & 63, wv = t >> 6, ln = lane & 15, qd = lane >> 4;
  int p = mt * 64 + wv * 16 + ln;
  if (p > 16559) p = 16559;
  const short* Ab = O1 + ((size_t)n * 16576 + p) * 192;
  short8 a[6];
#pragma unroll
  for (int kc = 0; kc < 6; ++kc) a[kc] = *(const short8*)&Ab[kc * 32 + qd * 8];
  __syncthreads();
  f32x4 z = {0.f, 0.f, 0.f, 0.f};
  f32x4 acc[6];
#pragma unroll
  for (int i = 0; i < 6; ++i) acc[i] = z;
#pragma unroll
  for (int kc = 0; kc < 6; ++kc) {
    int ko = kc * 32 + qd * 8;
#pragma unroll
    for (int nf = 0; nf < 6; ++nf) {
      short8 bv = *(const short8*)&Bl[(nf * 16 + ln) * 200 + ko];
      acc[nf] = MFMA16(a[kc], bv, acc[nf], 0, 0, 0);
    }
  }
  size_t p0 = (size_t)mt * 64 + wv * 16 + qd * 4;
  if (p0 < 16560) {
#pragma unroll
    for (int nf = 0; nf < 6; ++nf) {
      int j = nh * 96 + nf * 16 + ln;
      float bias = fB2[n * 192 + j];
      short4 v;
      float s0;
      s0 = acc[nf][0] + bias; s0 = fabsf(s0) > 0.01f ? copysignf(fabsf(s0) - 0.01f, s0) : 0.f; v.x = (short)f2b(s0);
      s0 = acc[nf][1] + bias; s0 = fabsf(s0) > 0.01f ? copysignf(fabsf(s0) - 0.01f, s0) : 0.f; v.y = (short)f2b(s0);
      s0 = acc[nf][2] + bias; s0 = fabsf(s0) > 0.01f ? copysignf(fabsf(s0) - 0.01f, s0) : 0.f; v.z = (short)f2b(s0);
      s0 = acc[nf][3] + bias; s0 = fabsf(s0) > 0.01f ? copysignf(fabsf(s0) - 0.01f, s0) : 0.f; v.w = (short)f2b(s0);
      *(short4*)&O2[((size_t)n * 192 + j) * 16576 + p0] = v;
    }
  }
}

// ---------------------------------------------------------------- T2 --------
__global__ __launch_bounds__(256) void t2_k(const short* __restrict__ O2,
                                            short* __restrict__ X3) {
  __shared__ short L[16 * 1488];
  int t = threadIdx.x;
  int gx = blockIdx.x;
  int ht = gx % 3; gx /= 3;
  int ot = gx % 6; gx /= 6;
  int rj = gx % 2; gx /= 2;
  int n = gx % 8;
  int b = gx / 8;
  int h0 = ht * 32;
  int nh = min(32, 90 - h0);
  int o0 = ot * 16;
  int posbase = (b * 90 + h0) * 46;
  int pa = posbase & ~7;
  int d = posbase - pa;
  int vlen = d + 46 * nh;
  int segs = (vlen + 7) / 8;
  for (int q = t; q < 16 * 186; q += 256) {
    int orl = q / 186, seg = q % 186;
    if (seg < segs) {
      short8 v = *(const short8*)&O2[((size_t)n * 192 + rj * 96 + o0 + orl) * 16576 +
                                     pa + seg * 8];
      int base = seg * 8;
      if (base >= d && base + 8 <= vlen) {
        *(short8*)&L[orl * 1488 + base] = v;
      } else {
#pragma unroll
        for (int i = 0; i < 8; ++i) {
          int col = base + i;
          L[orl * 1488 + col] = (col >= d && col < vlen) ? v[i] : (short)0;
        }
      }
    } else {
      short8 zz = {0, 0, 0, 0, 0, 0, 0, 0};
      *(short8*)&L[orl * 1488 + seg * 8] = zz;
    }
  }
  __syncthreads();
  short* dst = X3 + (size_t)b * 35328 * 192;
  for (int q = t; q < 46 * 64; q += 256) {
    int wp = q >> 6;
    int rem = q & 63;
    int orl = rem >> 2, seg = rem & 3;
    short8 v;
#pragma unroll
    for (int i = 0; i < 8; ++i) {
      int hrel = seg * 8 + i;
      v[i] = L[orl * 1488 + d + hrel * 46 + wp];
    }
    *(short8*)&dst[((size_t)wp * 768 + n * 96 + o0 + orl) * 192 + rj * 96 + h0 +
                   seg * 8] = v;
  }
}

// ---------------------------------------------------------------- S5 --------
// Per (b,h): C[c 64][w 192] = A(X4 gathered->LDS)[64][96] * Bt(cTwi LDS).
// Batched staging (exact unrolled trips, coalesced 128B runs on A);
// batched epilogue loads. LDS 53.2 KB -> 3 blocks/CU.
__global__ __launch_bounds__(256, 3) void s5_k(const short* __restrict__ X4,
                                               const short* __restrict__ cTwi,
                                               const float* __restrict__ x,
                                               float* __restrict__ out) {
  __shared__ short Bl[192 * 104];
  __shared__ short Al[64 * 104];
  int t = threadIdx.x;
  int bh = blockIdx.x;
  int c0 = blockIdx.y * 64;
  int b = bh / 90, h = bh % 90;
  // stage B: 192x12 short8 = 2304 / 256 = 9 exact.
  {
    short8 tb[9];
#pragma unroll
    for (int i = 0; i < 9; ++i) {
      int q = t + i * 256;
      int r = q / 12, s = q % 12;
      tb[i] = *(const short8*)&cTwi[r * 96 + s * 8];
    }
#pragma unroll
    for (int i = 0; i < 9; ++i) {
      int q = t + i * 256;
      int r = q / 12, s = q % 12;
      *(short8*)&Bl[r * 104 + s * 8] = tb[i];
    }
  }
  // stage A transposed: 96 k-rows x 8 segs = 768 / 256 = 3 exact, seg-fastest
  // (8 lanes = 128B contiguous run per k-row).
  {
    short8 ta[3];
    int kk[3], cc[3];
#pragma unroll
    for (int i = 0; i < 3; ++i) {
      int q = t + i * 256;
      int cs = q & 7, k = q >> 3;
      int ri = k / 48, wp = k % 48;
      if (wp > 45) wp = 45;
      ta[i] = *(const short8*)&X4[((size_t)b * 192 + ri * 96 + h) * 35328 +
                                  (size_t)wp * 768 + c0 + cs * 8];
      kk[i] = k; cc[i] = cs;
    }
#pragma unroll
    for (int i = 0; i < 3; ++i) {
#pragma unroll
      for (int j = 0; j < 8; ++j) Al[(cc[i] * 8 + j) * 104 + kk[i]] = ta[i][j];
    }
  }
  __syncthreads();
  int lane = t & 63, wv = t >> 6, ln = lane & 15, qd = lane >> 4;
  f32x4 z = {0.f, 0.f, 0.f, 0.f};
  f32x4 acc[12];
#pragma unroll
  for (int i = 0; i < 12; ++i) acc[i] = z;
  int arow = (wv * 16 + ln) * 104;
#pragma unroll
  for (int kc = 0; kc < 3; ++kc) {
    int ko = kc * 32 + qd * 8;
    short8 av = *(const short8*)&Al[arow + ko];
#pragma unroll
    for (int nf = 0; nf < 12; ++nf) {
      short8 bv = *(const short8*)&Bl[(nf * 16 + ln) * 104 + ko];
      acc[nf] = MFMA16(av, bv, acc[nf], 0, 0, 0);
    }
  }
  int cb = c0 + wv * 16 + qd * 4;
  const float* xr = x + (size_t)bh * 180 * 768;
  float* ob = out + (size_t)bh * 180 * 768;
  // batched residual loads (clamped addr), then stores.
  float4 xv[12];
#pragma unroll
  for (int nf = 0; nf < 12; ++nf) {
    int w = nf * 16 + ln;
    int wl = w < 180 ? w : 0;
    xv[nf] = *(const float4*)&xr[(size_t)wl * 768 + cb];
  }
#pragma unroll
  for (int nf = 0; nf < 12; ++nf) {
    int w = nf * 16 + ln;
    if (w < 180) {
      float4 o;
      o.x = acc[nf][0] + xv[nf].x;
      o.y = acc[nf][1] + xv[nf].y;
      o.z = acc[nf][2] + xv[nf].z;
      o.w = acc[nf][3] + xv[nf].w;
      *(float4*)&ob[(size_t)w * 768 + cb] = o;
    }
  }
}

}  // namespace

extern "C" void kernel_launch(void* const* d_in, const int* in_sizes, int n_in,
                              void* d_out, int out_size, void* d_ws, size_t ws_size,
                              hipStream_t stream) {
  const float* x = (const float*)d_in[0];
  const float* w1 = (const float*)d_in[1];
  const float* b1 = (const float*)d_in[2];
  const float* w2 = (const float*)d_in[3];
  const float* b2 = (const float*)d_in[4];
  float* out = (float*)d_out;

  size_t off = 0;
  auto carve = [&](size_t bytes) -> char* {
    char* p = (char*)d_ws + off;
    off += (bytes + 255) & ~(size_t)255;
    return p;
  };
  short* cTw = (short*)carve(96 * 192 * 2);
  short* cThf = (short*)carve(192 * 192 * 2);
  short* cThi = (short*)carve(192 * 192 * 2);
  short* cW1 = (short*)carve(8 * 192 * 192 * 2);
  short* cW2 = (short*)carve(8 * 192 * 192 * 2);
  short* cTwi = (short*)carve(192 * 96 * 2);
  float* fB1 = (float*)carve(8 * 192 * 4);
  float* fB2 = (float*)carve(8 * 192 * 4);
  const size_t SLOT = 27131904;  // shorts (= 4*192*35328)
  short* slotA = (short*)carve(SLOT * 2);
  short* slotB = (short*)carve(SLOT * 2);
  // liveness-based aliasing:
  short* X1a = slotA;  // S1 -> T1
  short* X1b = slotB;  // T1 -> S2
  short* X2 = slotA;   // S2 -> S3a
  short* O1 = slotB;   // S3a -> S3b
  short* O2 = slotA;   // S3b -> T2
  short* X3 = slotB;   // T2 -> S4
  short* X4 = slotA;   // S4 -> S5

  prep_k<<<512, 256, 0, stream>>>(cTw, cThf, cThi, cW1, cW2, cTwi, fB1, fB2,
                                  w1, b1, w2, b2);
  s1_k<<<dim3(360, 12), 256, 0, stream>>>(x, cTw, X1a);
  t1_k<<<dim3(368, 12), 256, 0, stream>>>(X1a, X1b);
  s24_k<<<dim3(552, 2, 4), 256, 0, stream>>>(X1b, cThf, X2);
  s3a_k<<<dim3(259, 16), 256, 0, stream>>>(X2, cW1, fB1, O1);
  s3b_k<<<dim3(259, 16), 256, 0, stream>>>(O1, cW2, fB2, O2);
  t2_k<<<dim3(1152), 256, 0, stream>>>(O2, X3);
  s24_k<<<dim3(552, 2, 4), 256, 0, stream>>>(X3, cThi, X4);
  s5_k<<<dim3(360, 12), 256, 0, stream>>>(X4, cTwi, x, out);
}

// Round 3
// 595.171 us; speedup vs baseline: 1.5393x; 1.0314x over previous
//
#include <hip/hip_runtime.h>
#include <math.h>

typedef __attribute__((ext_vector_type(8))) short short8;
typedef __attribute__((ext_vector_type(4))) float f32x4;

#define MFMA16 __builtin_amdgcn_mfma_f32_16x16x32_bf16

namespace {

constexpr float kI180 = 0.07453559924999299f;  // 1/sqrt(180)
constexpr float kI90  = 0.10540925533894598f;  // 1/sqrt(90)
constexpr float kTwoPi = 6.283185307179586f;

__device__ inline unsigned short f2b(float f) {
  unsigned u = __builtin_bit_cast(unsigned, f);
  u += 0x7fffu + ((u >> 16) & 1u);
  return (unsigned short)(u >> 16);
}

// Stage a 96x192 B-tile (k-contiguous) into LDS padded to stride 200.
// 2304 short8 / 256 threads = 9 exact trips, loads batched before writes.
__device__ __forceinline__ void stage_b(short* Bl, const short* src, int t) {
  short8 tb[9];
#pragma unroll
  for (int i = 0; i < 9; ++i) {
    int q = t + i * 256;
    int r = q / 24, s = q % 24;
    tb[i] = *(const short8*)&src[(size_t)r * 192 + s * 8];
  }
#pragma unroll
  for (int i = 0; i < 9; ++i) {
    int q = t + i * 256;
    int r = q / 24, s = q % 24;
    *(short8*)&Bl[r * 200 + s * 8] = tb[i];
  }
}

// Stage a 96x96 B-tile into LDS padded to stride 104 (1152 short8, 5 trips).
__device__ __forceinline__ void stage_b96(short* Bl, const short* src, int t) {
  short8 tb[5];
#pragma unroll
  for (int i = 0; i < 5; ++i) {
    int q = t + i * 256;
    int ql = q < 1152 ? q : 0;
    int r = ql / 12, s = ql % 12;
    tb[i] = *(const short8*)&src[r * 96 + s * 8];
  }
#pragma unroll
  for (int i = 0; i < 5; ++i) {
    int q = t + i * 256;
    if (q < 1152) {
      int r = q / 12, s = q % 12;
      *(short8*)&Bl[r * 104 + s * 8] = tb[i];
    }
  }
}

// 6-fragment MFMA sweep: acc[nf] = sum_kc a[kc] * Bl[nf-row], re-inits acc.
__device__ __forceinline__ void mfma6(f32x4* acc, const short8* a,
                                      const short* Bl, int ln, int qd) {
  f32x4 z = {0.f, 0.f, 0.f, 0.f};
#pragma unroll
  for (int i = 0; i < 6; ++i) acc[i] = z;
#pragma unroll
  for (int kc = 0; kc < 6; ++kc) {
    int ko = kc * 32 + qd * 8;
#pragma unroll
    for (int nf = 0; nf < 6; ++nf) {
      short8 bv = *(const short8*)&Bl[(nf * 16 + ln) * 200 + ko];
      acc[nf] = MFMA16(a[kc], bv, acc[nf], 0, 0, 0);
    }
  }
}

// ---------------------------------------------------------------- prep ------
// Blocks 0..15: cW1/cW2 via coalesced float4 loads + LDS transpose + coalesced
// short8 stores (runs every graph replay -> must be fast). Sign flip applied
// as bf16 XOR (exact, RNE is symmetric). Blocks 16..23: DFT matrices+biases.
__global__ __launch_bounds__(256) void prep_k(short* cTw, short* cThf, short* cThi,
                       short* cW1, short* cW2, short* cTwi, float* fB1, float* fB2,
                       const float* __restrict__ w1, const float* __restrict__ b1,
                       const float* __restrict__ w2, const float* __restrict__ b2) {
  int bx = blockIdx.x, t = threadIdx.x;
  if (bx < 16) {
    __shared__ short Wt[2 * 96 * 104];  // [plane][o][ci], stride 104 (16B-aligned rows)
    int n = bx & 7;
    const float* src = (bx < 8) ? w1 : w2;
    short* dstm = (bx < 8) ? cW1 : cW2;
#pragma unroll
    for (int pl = 0; pl < 2; ++pl) {
      const float* p = src + (size_t)(pl * 8 + n) * 9216;
      float4 tv[9];
#pragma unroll
      for (int i = 0; i < 9; ++i) tv[i] = *(const float4*)&p[(t + i * 256) * 4];
#pragma unroll
      for (int i = 0; i < 9; ++i) {
        int idx = t + i * 256;
        int ci = idx / 24, oq = idx % 24;
        short* wp_ = &Wt[pl * 96 * 104];
        wp_[(oq * 4 + 0) * 104 + ci] = (short)f2b(tv[i].x);
        wp_[(oq * 4 + 1) * 104 + ci] = (short)f2b(tv[i].y);
        wp_[(oq * 4 + 2) * 104 + ci] = (short)f2b(tv[i].z);
        wp_[(oq * 4 + 3) * 104 + ci] = (short)f2b(tv[i].w);
      }
    }
    __syncthreads();
#pragma unroll
    for (int u = 0; u < 18; ++u) {
      int idx = t + u * 256;  // short8 index over 192x192
      int jrow = idx / 24, sq = idx % 24;
      int rj = jrow / 96, o = jrow % 96;
      int ri = sq / 12, ciq = sq % 12;
      int pl = rj ^ ri;
      short8 v = *(const short8*)&Wt[pl * 96 * 104 + o * 104 + ciq * 8];
      if (rj == 0 && ri == 1) {
#pragma unroll
        for (int j = 0; j < 8; ++j) v[j] = (short)(v[j] ^ (short)0x8000);
      }
      *(short8*)&dstm[(size_t)n * 36864 + (size_t)jrow * 192 + sq * 8] = v;
    }
    return;
  }
  int gid = (bx - 16) * 256 + t;
  const int gs = 8 * 256;
  // cTw[96][192]: n=(ri,w') (48+48), k=w. forward W-DFT.
  for (int i = gid; i < 96 * 192; i += gs) {
    int n = i / 192, k = i % 192;
    int ri = n / 48, wp = n % 48;
    float v = 0.f;
    if (wp < 46 && k < 180) {
      int r = (k * wp) % 180;
      float s, c;
      sincosf(kTwoPi * (float)r / 180.f, &s, &c);
      v = (ri == 0) ? c * kI180 : -s * kI180;
    }
    cTw[i] = (short)f2b(v);
  }
  // cThf/cThi[192][192]: forward/inverse H-DFT.
  for (int i = gid; i < 192 * 192; i += gs) {
    int n = i / 192, k = i % 192;
    int rj = n / 96, hp = n % 96;
    int ri = k / 96, h = k % 96;
    float vf = 0.f, vi = 0.f;
    if (hp < 90 && h < 90) {
      int r = (h * hp) % 90;
      float s, c;
      sincosf(kTwoPi * (float)r / 90.f, &s, &c);
      c *= kI90; s *= kI90;
      vf = (rj == 0) ? ((ri == 0) ? c : s) : ((ri == 0) ? -s : c);
      vi = (rj == 0) ? ((ri == 0) ? c : -s) : ((ri == 0) ? s : c);
    }
    cThf[i] = (short)f2b(vf);
    cThi[i] = (short)f2b(vi);
  }
  // cTwi[192][96]: inverse W (real output, Hermitian fold).
  for (int i = gid; i < 192 * 96; i += gs) {
    int n = i / 96, k = i % 96;
    int ri = k / 48, wp = k % 48;
    float v = 0.f;
    if (n < 180 && wp < 46) {
      int r = (n * wp) % 180;
      float s, c;
      sincosf(kTwoPi * (float)r / 180.f, &s, &c);
      if (ri == 0) v = ((wp == 0) ? 1.f : 2.f) * c * kI180;
      else v = (wp == 0) ? 0.f : -2.f * s * kI180;
    }
    cTwi[i] = (short)f2b(v);
  }
  // biases fp32: fB[n][j=(rj,o)]
  for (int i = gid; i < 8 * 192; i += gs) {
    int n = i / 192, j = i % 192;
    int rj = j / 96, o = j % 96;
    fB1[i] = b1[(size_t)(rj * 8 + n) * 96 + o];
    fB2[i] = b2[(size_t)(rj * 8 + n) * 96 + o];
  }
}

// ---------------------------------------------------------------- S1 --------
// Per (b,h): C[c 64][n=(ri,w') 96] = A(x direct-gather)[64][192w] * Bt(cTw LDS).
__global__ __launch_bounds__(256, 4) void s1_k(const float* __restrict__ x,
                                               const short* __restrict__ cTw,
                                               short* __restrict__ X1a) {
  __shared__ short Bl[96 * 200];
  int t = threadIdx.x;
  int bh = blockIdx.x;
  int c0 = blockIdx.y * 64;
  stage_b(Bl, cTw, t);
  int lane = t & 63, wv = t >> 6, ln = lane & 15, qd = lane >> 4;
  int c = c0 + wv * 16 + ln;
  const float* xc = x + (size_t)bh * 180 * 768 + c;
  float xv[48];
#pragma unroll
  for (int kc = 0; kc < 6; ++kc) {
#pragma unroll
    for (int j = 0; j < 8; ++j) {
      int w = kc * 32 + qd * 8 + j;
      int wl = w < 180 ? w : 0;
      xv[kc * 8 + j] = xc[(size_t)wl * 768];
    }
  }
  short8 a[6];
#pragma unroll
  for (int kc = 0; kc < 6; ++kc) {
#pragma unroll
    for (int j = 0; j < 8; ++j) {
      int w = kc * 32 + qd * 8 + j;
      float v = (w < 180) ? xv[kc * 8 + j] : 0.f;
      a[kc][j] = (short)f2b(v);
    }
  }
  __syncthreads();
  f32x4 acc[6];
  mfma6(acc, a, Bl, ln, qd);
  short* dst = X1a + (size_t)bh * 96 * 768;
  int cbase = c0 + wv * 16 + qd * 4;
#pragma unroll
  for (int nf = 0; nf < 6; ++nf) {
    int n = nf * 16 + ln;
    short4 v;
    v.x = (short)f2b(acc[nf][0]);
    v.y = (short)f2b(acc[nf][1]);
    v.z = (short)f2b(acc[nf][2]);
    v.w = (short)f2b(acc[nf][3]);
    *(short4*)&dst[(size_t)n * 768 + cbase] = v;
  }
}

// ---------------------------------------------------------------- T1 --------
__global__ __launch_bounds__(256) void t1_k(const short* __restrict__ X1a,
                                            short* __restrict__ X1b) {
  __shared__ short L[64 * 104];
  unsigned* Ld = (unsigned*)L;
  int t = threadIdx.x;
  int gx = blockIdx.x;
  int c0 = blockIdx.y * 64;
  int b = gx / 92, r = gx % 92;
  int ri = r / 46, wp = r % 46;
  const short* src = X1a + ((size_t)(b * 90) * 96 + ri * 48 + wp) * 768 + c0;
  short8 r0a[2], r1a[2];
#pragma unroll
  for (int i = 0; i < 2; ++i) {
    int q = t + i * 256;
    int ql = q < 360 ? q : 0;
    int seg = ql & 7, hp = ql >> 3;
    int h0 = hp * 2;
    r0a[i] = *(const short8*)&src[(size_t)h0 * 73728 + seg * 8];
    r1a[i] = *(const short8*)&src[(size_t)(h0 + 1) * 73728 + seg * 8];
  }
#pragma unroll
  for (int i = 0; i < 2; ++i) {
    int q = t + i * 256;
    if (q < 360) {
      int seg = q & 7, hp = q >> 3;
#pragma unroll
      for (int j = 0; j < 8; ++j) {
        int cch = seg * 8 + j;
        Ld[cch * 52 + hp] = (unsigned)(unsigned short)r0a[i][j] |
                            ((unsigned)(unsigned short)r1a[i][j] << 16);
      }
    }
  }
  for (int q = t; q < 64 * 3; q += 256) {
    int cch = q / 3, hp = 45 + q % 3;
    Ld[cch * 52 + hp] = 0u;
  }
  __syncthreads();
  short* dst = X1b + (size_t)b * 35328 * 192 + ((size_t)wp * 768 + c0) * 192 + ri * 96;
  for (int q = t; q < 64 * 12; q += 256) {
    int cch = q / 12, seg = q % 12;
    short8 v = *(const short8*)&L[cch * 104 + seg * 8];
    *(short8*)&dst[(size_t)cch * 192 + seg * 8] = v;
  }
}

// ---------------------------------------------------------------- S2/S4 -----
// Per b: C[m 35328][n 192] = A[m][192] * Bt[n][192]; transposed store.
// nh merged: B staged in two 96-row phases, A-frags read ONCE (regs persist).
__global__ __launch_bounds__(256, 4) void s24_k(const short* __restrict__ Asrc,
                                                const short* __restrict__ Bsrc,
                                                short* __restrict__ dst) {
  __shared__ short Bl[96 * 200];
  int t = threadIdx.x;
  int mt = blockIdx.x, b = blockIdx.y;
  int lane = t & 63, wv = t >> 6, ln = lane & 15, qd = lane >> 4;
  const short* Ab = Asrc + ((size_t)b * 35328 + (size_t)mt * 64 + wv * 16 + ln) * 192;
  short8 a[6];
#pragma unroll
  for (int kc = 0; kc < 6; ++kc) a[kc] = *(const short8*)&Ab[kc * 32 + qd * 8];
  stage_b(Bl, Bsrc, t);
  __syncthreads();
  f32x4 acc[12];
  mfma6(acc, a, Bl, ln, qd);
  __syncthreads();
  stage_b(Bl, Bsrc + 96 * 192, t);
  __syncthreads();
  mfma6(acc + 6, a, Bl, ln, qd);
  size_t m0 = (size_t)mt * 64 + wv * 16 + qd * 4;
  short* db = dst + (size_t)b * 192 * 35328;
#pragma unroll
  for (int nf = 0; nf < 12; ++nf) {
    int n = (nf >= 6 ? 96 : 0) + (nf % 6) * 16 + ln;
    short4 v;
    v.x = (short)f2b(acc[nf][0]);
    v.y = (short)f2b(acc[nf][1]);
    v.z = (short)f2b(acc[nf][2]);
    v.w = (short)f2b(acc[nf][3]);
    *(short4*)&db[(size_t)n * 35328 + m0] = v;
  }
}

// ---------------------------------------------------------------- S3 --------
// Fused MLP: X2-gather once -> W1 (2 half-B phases) -> relu+bias -> LDS retile
// (aliases B buffer) -> layer-2 A frags -> W2 (2 phases) -> softshrink -> O2.
// No O1 HBM roundtrip. LDS 38.4 KB -> 4 blocks/CU.
__global__ __launch_bounds__(256, 4) void s3_k(const short* __restrict__ X2,
                                               const short* __restrict__ cW1,
                                               const short* __restrict__ cW2,
                                               const float* __restrict__ fB1,
                                               const float* __restrict__ fB2,
                                               short* __restrict__ O2) {
  __shared__ short Bl[96 * 200];
  int t = threadIdx.x;
  int mt = blockIdx.x, n = blockIdx.y;
  int lane = t & 63, wv = t >> 6, ln = lane & 15, qd = lane >> 4;
  int p = mt * 64 + wv * 16 + ln;
  if (p > 16559) p = 16559;
  int pb = p / 4140, rem = p % 4140;
  int hp = rem / 46, wp = rem % 46;
  const short* Ap = X2 + ((size_t)pb * 192 + hp) * 35328 + (size_t)wp * 768 + n * 96;
  short8 a[6];
#pragma unroll
  for (int kc = 0; kc < 6; ++kc) {
    int ko = kc * 32 + qd * 8;
    int ri = kc / 3;  // compile-time under unroll
    int kl = ko - ri * 96;
    a[kc] = *(const short8*)&Ap[(size_t)ri * 96 * 35328 + kl];
  }
  const short* B1 = cW1 + (size_t)n * 36864;
  const short* B2 = cW2 + (size_t)n * 36864;
  stage_b(Bl, B1, t);
  __syncthreads();
  f32x4 acc0[6], acc1[6];
  mfma6(acc0, a, Bl, ln, qd);
  __syncthreads();
  stage_b(Bl, B1 + 96 * 192, t);
  __syncthreads();
  mfma6(acc1, a, Bl, ln, qd);
  __syncthreads();
  // bias + relu -> retile into Bl as Rt[64 p][200]
#pragma unroll
  for (int nf = 0; nf < 6; ++nf) {
    float b0 = fB1[n * 192 + nf * 16 + ln];
    float b1v = fB1[n * 192 + 96 + nf * 16 + ln];
#pragma unroll
    for (int r = 0; r < 4; ++r) {
      int row = wv * 16 + qd * 4 + r;
      float v0 = acc0[nf][r] + b0;
      float v1 = acc1[nf][r] + b1v;
      v0 = v0 > 0.f ? v0 : 0.f;
      v1 = v1 > 0.f ? v1 : 0.f;
      Bl[row * 200 + nf * 16 + ln] = (short)f2b(v0);
      Bl[row * 200 + 96 + nf * 16 + ln] = (short)f2b(v1);
    }
  }
  __syncthreads();
  // layer-2 A fragments from retile
#pragma unroll
  for (int kc = 0; kc < 6; ++kc)
    a[kc] = *(const short8*)&Bl[(wv * 16 + ln) * 200 + kc * 32 + qd * 8];
  __syncthreads();
  stage_b(Bl, B2, t);
  __syncthreads();
  mfma6(acc0, a, Bl, ln, qd);
  __syncthreads();
  stage_b(Bl, B2 + 96 * 192, t);
  __syncthreads();
  mfma6(acc1, a, Bl, ln, qd);
  size_t p0 = (size_t)mt * 64 + wv * 16 + qd * 4;
  if (p0 < 16560) {
#pragma unroll
    for (int half = 0; half < 2; ++half) {
      f32x4* ac = half ? acc1 : acc0;
#pragma unroll
      for (int nf = 0; nf < 6; ++nf) {
        int j = half * 96 + nf * 16 + ln;
        float bias = fB2[n * 192 + j];
        short4 v;
        float s0;
        s0 = ac[nf][0] + bias; s0 = fabsf(s0) > 0.01f ? copysignf(fabsf(s0) - 0.01f, s0) : 0.f; v.x = (short)f2b(s0);
        s0 = ac[nf][1] + bias; s0 = fabsf(s0) > 0.01f ? copysignf(fabsf(s0) - 0.01f, s0) : 0.f; v.y = (short)f2b(s0);
        s0 = ac[nf][2] + bias; s0 = fabsf(s0) > 0.01f ? copysignf(fabsf(s0) - 0.01f, s0) : 0.f; v.z = (short)f2b(s0);
        s0 = ac[nf][3] + bias; s0 = fabsf(s0) > 0.01f ? copysignf(fabsf(s0) - 0.01f, s0) : 0.f; v.w = (short)f2b(s0);
        *(short4*)&O2[((size_t)n * 192 + j) * 16576 + p0] = v;
      }
    }
  }
}

// ---------------------------------------------------------------- T2 --------
__global__ __launch_bounds__(256) void t2_k(const short* __restrict__ O2,
                                            short* __restrict__ X3) {
  __shared__ short L[16 * 1488];
  int t = threadIdx.x;
  int gx = blockIdx.x;
  int ht = gx % 3; gx /= 3;
  int ot = gx % 6; gx /= 6;
  int rj = gx % 2; gx /= 2;
  int n = gx % 8;
  int b = gx / 8;
  int h0 = ht * 32;
  int nh = min(32, 90 - h0);
  int o0 = ot * 16;
  int posbase = (b * 90 + h0) * 46;
  int pa = posbase & ~7;
  int d = posbase - pa;
  int vlen = d + 46 * nh;
  int segs = (vlen + 7) / 8;
  for (int q = t; q < 16 * 186; q += 256) {
    int orl = q / 186, seg = q % 186;
    if (seg < segs) {
      short8 v = *(const short8*)&O2[((size_t)n * 192 + rj * 96 + o0 + orl) * 16576 +
                                     pa + seg * 8];
      int base = seg * 8;
      if (base >= d && base + 8 <= vlen) {
        *(short8*)&L[orl * 1488 + base] = v;
      } else {
#pragma unroll
        for (int i = 0; i < 8; ++i) {
          int col = base + i;
          L[orl * 1488 + col] = (col >= d && col < vlen) ? v[i] : (short)0;
        }
      }
    } else {
      short8 zz = {0, 0, 0, 0, 0, 0, 0, 0};
      *(short8*)&L[orl * 1488 + seg * 8] = zz;
    }
  }
  __syncthreads();
  short* dst = X3 + (size_t)b * 35328 * 192;
  for (int q = t; q < 46 * 64; q += 256) {
    int wp = q >> 6;
    int rem = q & 63;
    int orl = rem >> 2, seg = rem & 3;
    short8 v;
#pragma unroll
    for (int i = 0; i < 8; ++i) {
      int hrel = seg * 8 + i;
      v[i] = L[orl * 1488 + d + hrel * 46 + wp];
    }
    *(short8*)&dst[((size_t)wp * 768 + n * 96 + o0 + orl) * 192 + rj * 96 + h0 +
                   seg * 8] = v;
  }
}

// ---------------------------------------------------------------- S5 --------
// Per (b,h): C[c 64][w 192] = A(X4 gathered->LDS)[64][96] * Bt(cTwi).
// B two-phased (96 rows at a time): LDS 33.3 KB -> 4 blocks/CU.
__global__ __launch_bounds__(256, 4) void s5_k(const short* __restrict__ X4,
                                               const short* __restrict__ cTwi,
                                               const float* __restrict__ x,
                                               float* __restrict__ out) {
  __shared__ short Bl[96 * 104];
  __shared__ short Al[64 * 104];
  int t = threadIdx.x;
  int bh = blockIdx.x;
  int c0 = blockIdx.y * 64;
  int b = bh / 90, h = bh % 90;
  // stage A transposed: 3 exact trips, seg-fastest (128B runs).
  {
    short8 ta[3];
    int kk[3], cc[3];
#pragma unroll
    for (int i = 0; i < 3; ++i) {
      int q = t + i * 256;
      int cs = q & 7, k = q >> 3;
      int ri = k / 48, wp = k % 48;
      if (wp > 45) wp = 45;
      ta[i] = *(const short8*)&X4[((size_t)b * 192 + ri * 96 + h) * 35328 +
                                  (size_t)wp * 768 + c0 + cs * 8];
      kk[i] = k; cc[i] = cs;
    }
#pragma unroll
    for (int i = 0; i < 3; ++i) {
#pragma unroll
      for (int j = 0; j < 8; ++j) Al[(cc[i] * 8 + j) * 104 + kk[i]] = ta[i][j];
    }
  }
  stage_b96(Bl, cTwi, t);
  __syncthreads();
  int lane = t & 63, wv = t >> 6, ln = lane & 15, qd = lane >> 4;
  f32x4 z = {0.f, 0.f, 0.f, 0.f};
  f32x4 acc[12];
#pragma unroll
  for (int i = 0; i < 12; ++i) acc[i] = z;
  int arow = (wv * 16 + ln) * 104;
#pragma unroll
  for (int kc = 0; kc < 3; ++kc) {
    int ko = kc * 32 + qd * 8;
    short8 av = *(const short8*)&Al[arow + ko];
#pragma unroll
    for (int nf = 0; nf < 6; ++nf) {
      short8 bv = *(const short8*)&Bl[(nf * 16 + ln) * 104 + ko];
      acc[nf] = MFMA16(av, bv, acc[nf], 0, 0, 0);
    }
  }
  __syncthreads();
  stage_b96(Bl, cTwi + 96 * 96, t);
  __syncthreads();
#pragma unroll
  for (int kc = 0; kc < 3; ++kc) {
    int ko = kc * 32 + qd * 8;
    short8 av = *(const short8*)&Al[arow + ko];
#pragma unroll
    for (int nf = 6; nf < 12; ++nf) {
      short8 bv = *(const short8*)&Bl[((nf - 6) * 16 + ln) * 104 + ko];
      acc[nf] = MFMA16(av, bv, acc[nf], 0, 0, 0);
    }
  }
  int cb = c0 + wv * 16 + qd * 4;
  const float* xr = x + (size_t)bh * 180 * 768;
  float* ob = out + (size_t)bh * 180 * 768;
#pragma unroll
  for (int g = 0; g < 2; ++g) {
    float4 xv[6];
#pragma unroll
    for (int u = 0; u < 6; ++u) {
      int w = (g * 6 + u) * 16 + ln;
      int wl = w < 180 ? w : 0;
      xv[u] = *(const float4*)&xr[(size_t)wl * 768 + cb];
    }
#pragma unroll
    for (int u = 0; u < 6; ++u) {
      int nf = g * 6 + u;
      int w = nf * 16 + ln;
      if (w < 180) {
        float4 o;
        o.x = acc[nf][0] + xv[u].x;
        o.y = acc[nf][1] + xv[u].y;
        o.z = acc[nf][2] + xv[u].z;
        o.w = acc[nf][3] + xv[u].w;
        *(float4*)&ob[(size_t)w * 768 + cb] = o;
      }
    }
  }
}

}  // namespace

extern "C" void kernel_launch(void* const* d_in, const int* in_sizes, int n_in,
                              void* d_out, int out_size, void* d_ws, size_t ws_size,
                              hipStream_t stream) {
  const float* x = (const float*)d_in[0];
  const float* w1 = (const float*)d_in[1];
  const float* b1 = (const float*)d_in[2];
  const float* w2 = (const float*)d_in[3];
  const float* b2 = (const float*)d_in[4];
  float* out = (float*)d_out;

  size_t off = 0;
  auto carve = [&](size_t bytes) -> char* {
    char* p = (char*)d_ws + off;
    off += (bytes + 255) & ~(size_t)255;
    return p;
  };
  short* cTw = (short*)carve(96 * 192 * 2);
  short* cThf = (short*)carve(192 * 192 * 2);
  short* cThi = (short*)carve(192 * 192 * 2);
  short* cW1 = (short*)carve(8 * 192 * 192 * 2);
  short* cW2 = (short*)carve(8 * 192 * 192 * 2);
  short* cTwi = (short*)carve(192 * 96 * 2);
  float* fB1 = (float*)carve(8 * 192 * 4);
  float* fB2 = (float*)carve(8 * 192 * 4);
  const size_t SLOT = 27131904;  // shorts (= 4*192*35328)
  short* slotA = (short*)carve(SLOT * 2);
  short* slotB = (short*)carve(SLOT * 2);
  // liveness-based aliasing:
  short* X1a = slotA;  // S1 -> T1
  short* X1b = slotB;  // T1 -> S2
  short* X2 = slotA;   // S2 -> S3
  short* O2 = slotB;   // S3 -> T2
  short* X3 = slotA;   // T2 -> S4
  short* X4 = slotB;   // S4 -> S5

  prep_k<<<24, 256, 0, stream>>>(cTw, cThf, cThi, cW1, cW2, cTwi, fB1, fB2,
                                 w1, b1, w2, b2);
  s1_k<<<dim3(360, 12), 256, 0, stream>>>(x, cTw, X1a);
  t1_k<<<dim3(368, 12), 256, 0, stream>>>(X1a, X1b);
  s24_k<<<dim3(552, 4), 256, 0, stream>>>(X1b, cThf, X2);
  s3_k<<<dim3(259, 8), 256, 0, stream>>>(X2, cW1, cW2, fB1, fB2, O2);
  t2_k<<<dim3(1152), 256, 0, stream>>>(O2, X3);
  s24_k<<<dim3(552, 4), 256, 0, stream>>>(X3, cThi, X4);
  s5_k<<<dim3(360, 12), 256, 0, stream>>>(X4, cTwi, x, out);
}